// Round 6
// baseline (1420.478 us; speedup 1.0000x reference)
//
#include <hip/hip_runtime.h>

// 2-layer LSTM, B=512, T=1024, H=64 (tf LSTMCell, gates i,j,f,o, forget bias 1.0)
// One block (320 thr = 5 waves) per batch element.
//   Waves 0-3: gate g = wave id. Thread owns W1 column tid (registers).
//   Cell update REPLICATED in all 4 waves (bit-identical) -> 1 barrier/step.
//   Layer-2 dot h1 . W2[:,g] via DPP wave reduction (VALU, not LDS).
//   Wave 4 lane 0: serial layer-2 recurrence, one step behind (hidden in slack).
//
// Round 4/5 lesson: VGPR_Count=48 -> the backend REMATERIALIZED the 65
// weight loads into the t-loop (not spilled - no scratch traffic), making the
// kernel VMEM-issue bound (~1860 cy/step = 650 loads/step/CU). launch_bounds'
// 2nd arg only sets MIN waves/EU; the remat stage still chased max occupancy.
// Fix: amdgpu_waves_per_eu(2,3) caps the occupancy target (VGPR budget ~170),
// and an opaque empty-asm pins each loaded weight in a VGPR (asm results are
// not rematerializable).

#define TT 1024

__device__ __forceinline__ float fsig(float x) {
    return __builtin_amdgcn_rcpf(1.f + __expf(-x));
}
__device__ __forceinline__ float ftanh(float x) {
    // tanh(x) = 1 - 2/(1+e^{2x}); saturates via inf -> rcp -> 0
    return 1.f - 2.f * __builtin_amdgcn_rcpf(1.f + __expf(2.f * x));
}

template <int Ctrl, int Rmask>
__device__ __forceinline__ float dpp_add(float x) {
    int t = __builtin_amdgcn_update_dpp(0, __float_as_int(x), Ctrl, Rmask, 0xf, true);
    return x + __int_as_float(t);
}
// Sum across 64 lanes; result valid in lane 63. 6 dependent VALU ops.
__device__ __forceinline__ float wave_sum64(float x) {
    x = dpp_add<0x111, 0xf>(x); // row_shr:1
    x = dpp_add<0x112, 0xf>(x); // row_shr:2
    x = dpp_add<0x114, 0xf>(x); // row_shr:4
    x = dpp_add<0x118, 0xf>(x); // row_shr:8  -> lane15 of each row has row sum
    x = dpp_add<0x142, 0xa>(x); // row_bcast:15 -> rows 1,3
    x = dpp_add<0x143, 0xc>(x); // row_bcast:31 -> rows 2,3; lane63 = total
    return x;
}

__global__ __launch_bounds__(320)
__attribute__((amdgpu_waves_per_eu(2, 3)))
void lstm2_kernel(
    const float* __restrict__ x,    // [B, T]
    const float* __restrict__ W1,   // [65, 256]; row0 = x, rows 1..64 = h1
    const float* __restrict__ b1,   // [256]
    const float* __restrict__ W2,   // [65, 4]; rows 0..63 = h1, row 64 = h2
    const float* __restrict__ b2,   // [4]
    float* __restrict__ y)          // [B, T]
{
    __shared__ __align__(16) float xs[TT];
    __shared__ __align__(16) float h1s[64];
    __shared__ __align__(16) float gs[2][4][64];  // parity double-buffered gates
    __shared__ float dbuf[2][4];                  // parity-buffered layer-2 dots

    const int tid  = threadIdx.x;
    const int b    = blockIdx.x;
    const int lane = tid & 63;
    const int g    = tid >> 6;   // 0..3 = compute waves, 4 = layer-2 wave

    // stage x row into LDS (coalesced float4, threads 0..255)
    if (tid < 256) {
        const float4* xrow = (const float4*)(x + (size_t)b * TT);
        ((float4*)xs)[tid] = xrow[tid];
    }

    // per-thread layer-1 weights: column tid (65 floats, pinned in registers)
    float w[65];
    float bias = 0.f, w2g = 0.f;
    if (g < 4) {
#pragma unroll
        for (int k = 0; k < 65; ++k) {
            w[k] = W1[k * 256 + tid];
            asm volatile("" : "+v"(w[k]));   // opaque: kills rematerialization
        }
        bias = b1[tid];
        w2g  = W2[lane * 4 + g];   // W2[lane][g] for the DPP dot product
    }

    // layer-2 scalar constants (used by wave 4; cheap scalar loads everywhere)
    const float w2h0 = W2[256], w2h1 = W2[257], w2h2 = W2[258], w2h3 = W2[259];
    const float b20 = b2[0], b21 = b2[1], b22 = b2[2], b23 = b2[3];

    float c1 = 0.f;              // per-wave replicated cell state of unit `lane`
    float c2 = 0.f, h2 = 0.f;    // wave-4 layer-2 state

    if (tid < 64) h1s[tid] = 0.f;
    __syncthreads();

    float* yrow = y + (size_t)b * TT;

    for (int t = 0; t < TT; ++t) {
        const int par = t & 1;
        if (g < 4) {
            // ---- phase 1: matvec + activation for gate column tid ----
            const float xt = xs[t];
            float a0 = fmaf(xt, w[0], bias), a1 = 0.f, a2 = 0.f, a3 = 0.f;
#pragma unroll
            for (int kk = 0; kk < 16; ++kk) {
                float4 h4 = ((const float4*)h1s)[kk];   // same-addr broadcast read
                a0 = fmaf(h4.x, w[1 + 4*kk + 0], a0);
                a1 = fmaf(h4.y, w[1 + 4*kk + 1], a1);
                a2 = fmaf(h4.z, w[1 + 4*kk + 2], a2);
                a3 = fmaf(h4.w, w[1 + 4*kk + 3], a3);
            }
            float gate = (a0 + a1) + (a2 + a3);
            float act;
            if (g == 1)      act = ftanh(gate);          // j
            else if (g == 2) act = fsig(gate + 1.f);     // f (+forget bias)
            else             act = fsig(gate);           // i, o
            gs[par][g][lane] = act;
        }
        __syncthreads();   // the ONLY barrier per step
        if (g < 4) {
            // ---- phase 2: replicated cell update (identical in waves 0-3) ----
            const float i_ = gs[par][0][lane], j_ = gs[par][1][lane];
            const float f_ = gs[par][2][lane], o_ = gs[par][3][lane];
            c1 = fmaf(c1, f_, i_ * j_);
            const float h1 = ftanh(c1) * o_;
            h1s[lane] = h1;                 // benign same-value multi-wave write
            // layer-2 dot for gate g (off the h1 critical path)
            float p = wave_sum64(h1 * w2g);
            if (lane == 63) dbuf[par][g] = p;
        } else if (t > 0 && lane == 0) {
            // ---- wave 4: layer-2 recurrence for step t-1 ----
            const int pp = par ^ 1;
            const float d0 = dbuf[pp][0], d1 = dbuf[pp][1];
            const float d2 = dbuf[pp][2], d3 = dbuf[pp][3];
            const float i2 = fsig (fmaf(h2, w2h0, d0) + b20);
            const float j2 = ftanh(fmaf(h2, w2h1, d1) + b21);
            const float f2 = fsig (fmaf(h2, w2h2, d2) + b22 + 1.f);
            const float o2 = fsig (fmaf(h2, w2h3, d3) + b23);
            c2 = fmaf(c2, f2, i2 * j2);
            h2 = ftanh(c2) * o2;
            yrow[t - 1] = h2;
        }
    }
    __syncthreads();
    if (g == 4 && lane == 0) {   // final layer-2 step (t = TT-1)
        const int pp = (TT - 1) & 1;
        const float d0 = dbuf[pp][0], d1 = dbuf[pp][1];
        const float d2 = dbuf[pp][2], d3 = dbuf[pp][3];
        const float i2 = fsig (fmaf(h2, w2h0, d0) + b20);
        const float j2 = ftanh(fmaf(h2, w2h1, d1) + b21);
        const float f2 = fsig (fmaf(h2, w2h2, d2) + b22 + 1.f);
        const float o2 = fsig (fmaf(h2, w2h3, d3) + b23);
        c2 = fmaf(c2, f2, i2 * j2);
        h2 = ftanh(c2) * o2;
        yrow[TT - 1] = h2;
    }
}

extern "C" void kernel_launch(void* const* d_in, const int* in_sizes, int n_in,
                              void* d_out, int out_size, void* d_ws, size_t ws_size,
                              hipStream_t stream) {
    const float* x  = (const float*)d_in[0];
    const float* W1 = (const float*)d_in[1];
    const float* b1 = (const float*)d_in[2];
    const float* W2 = (const float*)d_in[3];
    const float* b2 = (const float*)d_in[4];
    float* y = (float*)d_out;
    lstm2_kernel<<<512, 320, 0, stream>>>(x, W1, b1, W2, b2, y);
}

// Round 8
// 779.159 us; speedup vs baseline: 1.8231x; 1.8231x over previous
//
#include <hip/hip_runtime.h>

// 2-layer LSTM, B=512, T=1024, H=64 (tf LSTMCell, gates i,j,f,o, forget bias 1.0)
// One block (576 thr = 9 waves) per batch element.
//   Waves 0-7: compute. Wave w owns gate columns [32w, 32w+32); gate g = w>>1.
//   SPLIT-K: lanes 0-31 hold W1 rows 0..32 (incl x-row + bias), lanes 32-63
//   hold rows 33..64 (w[0]=0, bias=0 -> branch-free). Halves combined with one
//   __shfl_xor(p,32) in-wave -> still ONE barrier/step.
//   33 weights/thread keeps natural VGPR use < 64 so the backend does NOT
//   rematerialize weight loads into the t-loop (rounds 4-6 lesson: 65/thread
//   forced remat -> L1-BW bound; pinning forced spills -> worse).
//   Cell update replicated in all 8 waves (bit-identical same-value writes).
//   Layer-2 dot h1.W2[:,g] via DPP wave reduction on waves 0-3.
//   Wave 8 lane 0: serial layer-2 recurrence, one step behind (hidden).

#define TT 1024

__device__ __forceinline__ float fsig(float x) {
    return __builtin_amdgcn_rcpf(1.f + __expf(-x));
}
__device__ __forceinline__ float ftanh(float x) {
    // tanh(x) = 1 - 2/(1+e^{2x}); saturates via inf -> rcp -> 0
    return 1.f - 2.f * __builtin_amdgcn_rcpf(1.f + __expf(2.f * x));
}

template <int Ctrl, int Rmask>
__device__ __forceinline__ float dpp_add(float x) {
    int t = __builtin_amdgcn_update_dpp(0, __float_as_int(x), Ctrl, Rmask, 0xf, true);
    return x + __int_as_float(t);
}
// Sum across 64 lanes; result valid in lane 63. 6 dependent VALU ops.
__device__ __forceinline__ float wave_sum64(float x) {
    x = dpp_add<0x111, 0xf>(x); // row_shr:1
    x = dpp_add<0x112, 0xf>(x); // row_shr:2
    x = dpp_add<0x114, 0xf>(x); // row_shr:4
    x = dpp_add<0x118, 0xf>(x); // row_shr:8  -> lane15 of each row has row sum
    x = dpp_add<0x142, 0xa>(x); // row_bcast:15 -> rows 1,3
    x = dpp_add<0x143, 0xc>(x); // row_bcast:31 -> rows 2,3; lane63 = total
    return x;
}

__global__ __launch_bounds__(576) void lstm2_kernel(
    const float* __restrict__ x,    // [B, T]
    const float* __restrict__ W1,   // [65, 256]; row0 = x, rows 1..64 = h1
    const float* __restrict__ b1,   // [256]
    const float* __restrict__ W2,   // [65, 4]; rows 0..63 = h1, row 64 = h2
    const float* __restrict__ b2,   // [4]
    float* __restrict__ y)          // [B, T]
{
    __shared__ __align__(16) float xs[TT];
    __shared__ __align__(16) float h1s[64];
    __shared__ __align__(16) float gs[2][4][64];  // parity double-buffered gates
    __shared__ float dbuf[2][4];                  // parity-buffered layer-2 dots

    const int tid  = threadIdx.x;
    const int b    = blockIdx.x;
    const int lane = tid & 63;
    const int cw   = tid >> 6;        // 0..7 compute waves, 8 = layer-2 wave
    const int half = lane >> 5;       // split-k half within the wave
    const int l31  = lane & 31;
    const int col  = (cw << 5) | l31; // gate column (cw<8)
    const int g    = cw >> 1;         // gate id (wave-uniform)

    // stage x row into LDS (coalesced float4)
    if (tid < 256) {
        ((float4*)xs)[tid] = ((const float4*)(x + (size_t)b * TT))[tid];
    }

    // per-thread layer-1 weights: 33 floats (half a column) in registers
    float w[33];
    float bias = 0.f, w2g = 0.f;
    if (cw < 8) {
        if (half == 0) {
            w[0] = W1[col];          // x-row weight
            bias = b1[col];
#pragma unroll
            for (int j = 1; j <= 32; ++j) w[j] = W1[j * 256 + col];       // rows 1..32
        } else {
            w[0] = 0.f;              // no x term, no bias in upper half
#pragma unroll
            for (int j = 1; j <= 32; ++j) w[j] = W1[(32 + j) * 256 + col]; // rows 33..64
        }
    }
    if (cw < 4) w2g = W2[lane * 4 + cw];   // W2[lane][cw] for the DPP dot

    // layer-2 scalar constants
    const float w2h0 = W2[256], w2h1 = W2[257], w2h2 = W2[258], w2h3 = W2[259];
    const float b20 = b2[0], b21 = b2[1], b22 = b2[2], b23 = b2[3];

    float c1 = 0.f;              // replicated cell state of hidden unit `lane`
    float c2 = 0.f, h2 = 0.f;    // wave-8 layer-2 state

    if (tid < 64) h1s[tid] = 0.f;
    __syncthreads();

    float* yrow = y + (size_t)b * TT;
    const int hbase = half << 3;   // float4 base index into h1s: 0 or 8

    for (int t = 0; t < TT; ++t) {
        const int par = t & 1;
        if (cw < 8) {
            // ---- phase 1: half-column matvec (33 FMA) ----
            const float xt = xs[t];
            float a0 = fmaf(xt, w[0], bias), a1 = 0.f, a2 = 0.f, a3 = 0.f;
#pragma unroll
            for (int q = 0; q < 8; ++q) {
                // 2 distinct addrs per wave -> 2-way LDS broadcast (free)
                float4 h4 = ((const float4*)h1s)[hbase + q];
                a0 = fmaf(h4.x, w[1 + 4*q], a0);
                a1 = fmaf(h4.y, w[2 + 4*q], a1);
                a2 = fmaf(h4.z, w[3 + 4*q], a2);
                a3 = fmaf(h4.w, w[4 + 4*q], a3);
            }
            float p = (a0 + a1) + (a2 + a3);
            p += __shfl_xor(p, 32);          // combine the two k-halves in-wave
            float act;
            if (g == 1)      act = ftanh(p);          // j
            else if (g == 2) act = fsig(p + 1.f);     // f (+forget bias)
            else             act = fsig(p);           // i, o
            if (half == 0) gs[par][g][(cw & 1) * 32 + l31] = act;
        }
        __syncthreads();   // the ONLY barrier per step
        if (cw < 8) {
            // ---- phase 2: replicated cell update (identical in waves 0-7) ----
            const float i_ = gs[par][0][lane], j_ = gs[par][1][lane];
            const float f_ = gs[par][2][lane], o_ = gs[par][3][lane];
            c1 = fmaf(c1, f_, i_ * j_);
            const float h1 = ftanh(c1) * o_;
            h1s[lane] = h1;                 // benign same-value multi-wave write
            if (cw < 4) {                   // layer-2 dot for gate cw
                float p = wave_sum64(h1 * w2g);
                if (lane == 63) dbuf[par][cw] = p;
            }
        } else if (t > 0 && lane == 0) {
            // ---- wave 8: layer-2 recurrence for step t-1 ----
            const int pp = par ^ 1;
            const float d0 = dbuf[pp][0], d1 = dbuf[pp][1];
            const float d2 = dbuf[pp][2], d3 = dbuf[pp][3];
            const float i2 = fsig (fmaf(h2, w2h0, d0) + b20);
            const float j2 = ftanh(fmaf(h2, w2h1, d1) + b21);
            const float f2 = fsig (fmaf(h2, w2h2, d2) + b22 + 1.f);
            const float o2 = fsig (fmaf(h2, w2h3, d3) + b23);
            c2 = fmaf(c2, f2, i2 * j2);
            h2 = ftanh(c2) * o2;
            yrow[t - 1] = h2;
        }
    }
    __syncthreads();
    if (cw == 8 && lane == 0) {   // final layer-2 step (t = TT-1)
        const int pp = (TT - 1) & 1;
        const float d0 = dbuf[pp][0], d1 = dbuf[pp][1];
        const float d2 = dbuf[pp][2], d3 = dbuf[pp][3];
        const float i2 = fsig (fmaf(h2, w2h0, d0) + b20);
        const float j2 = ftanh(fmaf(h2, w2h1, d1) + b21);
        const float f2 = fsig (fmaf(h2, w2h2, d2) + b22 + 1.f);
        const float o2 = fsig (fmaf(h2, w2h3, d3) + b23);
        c2 = fmaf(c2, f2, i2 * j2);
        h2 = ftanh(c2) * o2;
        yrow[TT - 1] = h2;
    }
}

extern "C" void kernel_launch(void* const* d_in, const int* in_sizes, int n_in,
                              void* d_out, int out_size, void* d_ws, size_t ws_size,
                              hipStream_t stream) {
    const float* x  = (const float*)d_in[0];
    const float* W1 = (const float*)d_in[1];
    const float* b1 = (const float*)d_in[2];
    const float* W2 = (const float*)d_in[3];
    const float* b2 = (const float*)d_in[4];
    float* y = (float*)d_out;
    lstm2_kernel<<<512, 576, 0, stream>>>(x, W1, b1, W2, b2, y);
}